// Round 12
// baseline (210.127 us; speedup 1.0000x reference)
//
#include <hip/hip_runtime.h>
#include <stdint.h>

#define BB 2
#define SS 2048
#define HH 1024
#define NHEAD 16
#define HDIM 64

constexpr int   BSROWS = BB * SS;   // 4096
constexpr float SCALE  = 0.125f;    // 1/sqrt(64)
constexpr float LOG2E  = 1.4426950408889634f;
constexpr float SL     = SCALE * LOG2E;

typedef __bf16 bf16;
typedef __attribute__((ext_vector_type(8))) __bf16 bf16x8;
typedef __attribute__((ext_vector_type(4))) __bf16 bf16x4;
typedef __attribute__((ext_vector_type(4))) float  f32x4;

#define MFMA16(a, b, c) __builtin_amdgcn_mfma_f32_16x16x32_bf16((a), (b), (c), 0, 0, 0)

__device__ __forceinline__ void gload_lds16(const void* g, void* l) {
  __builtin_amdgcn_global_load_lds((const __attribute__((address_space(1))) void*)g,
                                   (__attribute__((address_space(3))) void*)l, 16, 0, 0);
}

// ---------------------------------------------------------------- convert inputs (bias pre-scaled by LOG2E)
__global__ __launch_bounds__(256) void cvt_in(const float* __restrict__ q, const float* __restrict__ k,
                                              const float* __restrict__ v, const int* __restrict__ mask,
                                              bf16* __restrict__ xq, bf16* __restrict__ xk,
                                              bf16* __restrict__ xv, float* __restrict__ bias2) {
  int i = blockIdx.x * 256 + threadIdx.x;
  int e = i * 4;
  f32x4 a = *(const f32x4*)(q + e);
  f32x4 b = *(const f32x4*)(k + e);
  f32x4 c = *(const f32x4*)(v + e);
  *(bf16x4*)(xq + e) = __builtin_convertvector(a, bf16x4);
  *(bf16x4*)(xk + e) = __builtin_convertvector(b, bf16x4);
  *(bf16x4*)(xv + e) = __builtin_convertvector(c, bf16x4);
  if (i < BB * SS) bias2[i] = mask[i] ? 0.0f : -1e9f * LOG2E;
}

// ---------------------------------------------------------------- transpose + cast weights: Wt[n][k] = W[k][n]
__global__ __launch_bounds__(256) void cvt_wt(const float* __restrict__ Wq, const float* __restrict__ Wk,
                                              const float* __restrict__ Wv, const float* __restrict__ Wo,
                                              bf16* __restrict__ Wt) {
  __shared__ float tile[32][33];
  int z = blockIdx.z;
  const float* W = (z == 0) ? Wq : (z == 1) ? Wk : (z == 2) ? Wv : Wo;
  bf16* out = Wt + (size_t)z * HH * HH;
  int bx = blockIdx.x * 32, by = blockIdx.y * 32;
  int tx = threadIdx.x, ty = threadIdx.y;
#pragma unroll
  for (int j = 0; j < 32; j += 8)
    tile[ty + j][tx] = W[(size_t)(by + ty + j) * HH + bx + tx];
  __syncthreads();
#pragma unroll
  for (int j = 0; j < 32; j += 8)
    out[(size_t)(bx + ty + j) * HH + by + tx] = (bf16)tile[tx][ty + j];
}

// ---------------------------------------------------------------- 128x128 bf16 GEMM (m97 structure + XCD swizzle)
__global__ __launch_bounds__(256) void gemm128(const bf16* __restrict__ Abase, const bf16* __restrict__ Btbase,
                                               bf16* __restrict__ Qo, bf16* __restrict__ Ko,
                                               bf16* __restrict__ Vto, float* __restrict__ outF, int mode) {
  // XCD-aware swizzle: hw id -> logical tile so each XCD gets a contiguous chunk (nwg % 8 == 0)
  int id  = blockIdx.x + 8 * blockIdx.y + 256 * blockIdx.z;
  int nwg = 256 * gridDim.z;
  int sw  = (id & 7) * (nwg >> 3) + (id >> 3);
  int bx  = sw & 7, by = (sw >> 3) & 31, bz = sw >> 8;

  int zmode = (mode < 0) ? bz : mode;
  const bf16* A  = Abase  + (mode < 0 ? (size_t)bz * BSROWS * HH : 0);
  const bf16* Bt = Btbase + (mode < 0 ? (size_t)bz * HH * HH : 0);

  __shared__ __align__(16) bf16 lA[128 * 32];
  __shared__ __align__(16) bf16 lB[128 * 32];

  int t = threadIdx.x;
  int w = t >> 6, l = t & 63, lg = l >> 4, lr = l & 15;
  int m0 = by * 128, n0 = bx * 128;
  int wr = (w >> 1) * 64, wc = (w & 1) * 64;

  f32x4 zero4 = {0.f, 0.f, 0.f, 0.f};
  f32x4 acc[4][4];
#pragma unroll
  for (int i = 0; i < 4; i++)
#pragma unroll
    for (int j = 0; j < 4; j++) acc[i][j] = zero4;

  for (int k0 = 0; k0 < HH; k0 += 32) {
#pragma unroll
    for (int i = 0; i < 2; i++) {
      int idx = i * 256 + t;
      gload_lds16(A  + (size_t)(m0 + (idx >> 2)) * HH + k0 + (idx & 3) * 8, &lA[(i * 256 + w * 64) * 8]);
      gload_lds16(Bt + (size_t)(n0 + (idx >> 2)) * HH + k0 + (idx & 3) * 8, &lB[(i * 256 + w * 64) * 8]);
    }
    __syncthreads();
    bf16x8 af[4], bq[4];
#pragma unroll
    for (int mi = 0; mi < 4; mi++) af[mi] = *(const bf16x8*)&lA[(wr + mi * 16 + lr) * 32 + lg * 8];
#pragma unroll
    for (int ni = 0; ni < 4; ni++) bq[ni] = *(const bf16x8*)&lB[(wc + ni * 16 + lr) * 32 + lg * 8];
#pragma unroll
    for (int mi = 0; mi < 4; mi++)
#pragma unroll
      for (int ni = 0; ni < 4; ni++)
        acc[mi][ni] = MFMA16(af[mi], bq[ni], acc[mi][ni]);
    __syncthreads();
  }

#pragma unroll
  for (int mi = 0; mi < 4; mi++) {
    int row0 = m0 + wr + mi * 16 + lg * 4;
#pragma unroll
    for (int ni = 0; ni < 4; ni++) {
      int col = n0 + wc + ni * 16 + lr;
      if (zmode == 3) {
#pragma unroll
        for (int r = 0; r < 4; r++) outF[(size_t)(row0 + r) * HH + col] = acc[mi][ni][r];
      } else if (zmode == 2) {
        int b = row0 >> 11, s0 = row0 & (SS - 1);
        int h = col >> 6, d = col & 63;
        bf16x4 pk;
#pragma unroll
        for (int r = 0; r < 4; r++) pk[r] = (bf16)acc[mi][ni][r];
        *(bf16x4*)&Vto[((size_t)(b * NHEAD + h) * HDIM + d) * SS + s0] = pk;
      } else {
        bf16* dst = (zmode == 0) ? Qo : Ko;
        int h = col >> 6, d = col & 63;
#pragma unroll
        for (int r = 0; r < 4; r++) {
          int row = row0 + r;
          int b = row >> 11, s = row & (SS - 1);
          dst[((size_t)(b * NHEAD + h) * SS + s) * HDIM + d] = (bf16)acc[mi][ni][r];
        }
      }
    }
  }
}

// ---------------------------------------------------------------- flash (m=0), DMA-staged double-buffered K/V,
// ONE barrier per tile. LDS linear [64][64]; bank behavior preserved by pre-swizzled source chunks:
// lane loads global chunk (l&7)^((l>>3)&7); reads XOR chunk index with row&7.
__global__ __launch_bounds__(256, 2) void attn_pv(const bf16* __restrict__ Q, const bf16* __restrict__ K,
                                                  const bf16* __restrict__ Vt, const float* __restrict__ bias2,
                                                  float* __restrict__ invl, bf16* __restrict__ ctx) {
  int b = blockIdx.z, h = blockIdx.y, q0 = blockIdx.x * 128;
  int t = threadIdx.x, w = t >> 6, l = t & 63, lg = l >> 4, lr = l & 15;
  size_t hb = ((size_t)b * NHEAD + h) * SS;
  const bf16* Qh = Q + hb * HDIM;
  const bf16* Kh = K + hb * HDIM;
  const bf16* Vh = Vt + ((size_t)b * NHEAD + h) * HDIM * SS;
  const float* biasb = bias2 + b * SS;

  __shared__ __align__(16) bf16 sK[2][64][64];
  __shared__ __align__(16) bf16 sV[2][64][64];
  __shared__ __align__(16) bf16 lp[4][32][72];

  int rloc = l >> 3;                       // staging row within 8-row DMA slice
  int csw  = (l & 7) ^ (rloc & 7);         // pre-swizzled source chunk
  int swz  = lr & 7;                       // read-side XOR key (row&7 for rows ni*16+lr)

  int qa = q0 + w * 32;                    // this wave's 32 q-rows
  int rowa = qa + lr, rowb = qa + 16 + lr;
  bf16x8 qf0a = *(const bf16x8*)&Qh[(size_t)rowa * HDIM + lg * 8];
  bf16x8 qf1a = *(const bf16x8*)&Qh[(size_t)rowa * HDIM + 32 + lg * 8];
  bf16x8 qf0b = *(const bf16x8*)&Qh[(size_t)rowb * HDIM + lg * 8];
  bf16x8 qf1b = *(const bf16x8*)&Qh[(size_t)rowb * HDIM + 32 + lg * 8];

  f32x4 zero4 = {0.f, 0.f, 0.f, 0.f};
  f32x4 lacca = zero4, laccb = zero4;      // per-lane partial denominators
  f32x4 ctxa[4], ctxb[4];
#pragma unroll
  for (int nd = 0; nd < 4; nd++) { ctxa[nd] = zero4; ctxb[nd] = zero4; }

  // prologue: DMA-stage tile 0 into buffer 0 (each wave stages its 16 rows of K and V)
#pragma unroll
  for (int i = 0; i < 2; i++) {
    int rs = w * 16 + i * 8;
    gload_lds16(Kh + (size_t)(rs + rloc) * HDIM + csw * 8, &sK[0][rs][0]);
    gload_lds16(Vh + (size_t)(rs + rloc) * SS + csw * 8,   &sV[0][rs][0]);
  }
  __syncthreads();

  for (int kt = 0; kt < 32; kt++) {
    int k0 = kt * 64, cur = kt & 1;
    if (kt < 31) {                         // issue next tile's DMA first; overlaps compute
      int kn = k0 + 64;
#pragma unroll
      for (int i = 0; i < 2; i++) {
        int rs = w * 16 + i * 8;
        gload_lds16(Kh + (size_t)(kn + rs + rloc) * HDIM + csw * 8, &sK[cur ^ 1][rs][0]);
        gload_lds16(Vh + (size_t)(rs + rloc) * SS + kn + csw * 8,   &sV[cur ^ 1][rs][0]);
      }
    }
    // ---- swapped QK^T (XOR-swizzled reads): acc[ni][r] = S[kcol][qrow]
    f32x4 acca[4], accb[4];
#pragma unroll
    for (int ni = 0; ni < 4; ni++) {
      bf16x8 kf0 = *(const bf16x8*)&sK[cur][ni * 16 + lr][(lg ^ swz) * 8];
      bf16x8 kf1 = *(const bf16x8*)&sK[cur][ni * 16 + lr][((4 + lg) ^ swz) * 8];
      acca[ni] = MFMA16(kf1, qf1a, MFMA16(kf0, qf0a, zero4));
      accb[ni] = MFMA16(kf1, qf1b, MFMA16(kf0, qf0b, zero4));
    }
    // ---- p = exp2(s*SL + bias2), lane-local; accumulate denominator partials
    f32x4 pa4[4], pb4[4];
#pragma unroll
    for (int ni = 0; ni < 4; ni++) {
      f32x4 bv = *(const f32x4*)&biasb[k0 + ni * 16 + lg * 4];
      f32x4 za = acca[ni] * SL + bv;
      f32x4 zb = accb[ni] * SL + bv;
#pragma unroll
      for (int r = 0; r < 4; r++) {
        pa4[ni][r] = __builtin_amdgcn_exp2f(za[r]);
        pb4[ni][r] = __builtin_amdgcn_exp2f(zb[r]);
      }
    }
    lacca += (pa4[0] + pa4[1]) + (pa4[2] + pa4[3]);
    laccb += (pb4[0] + pb4[1]) + (pb4[2] + pb4[3]);
#pragma unroll
    for (int ni = 0; ni < 4; ni++) {
      *(bf16x4*)&lp[w][lr][ni * 16 + lg * 4]      = __builtin_convertvector(pa4[ni], bf16x4);
      *(bf16x4*)&lp[w][16 + lr][ni * 16 + lg * 4] = __builtin_convertvector(pb4[ni], bf16x4);
    }
    // ---- PV (V frags XOR-swizzled, shared by a/b)
#pragma unroll
    for (int kk = 0; kk < 2; kk++) {
      bf16x8 paa = *(const bf16x8*)&lp[w][lr][kk * 32 + lg * 8];
      bf16x8 pab = *(const bf16x8*)&lp[w][16 + lr][kk * 32 + lg * 8];
#pragma unroll
      for (int nd = 0; nd < 4; nd++) {
        bf16x8 vf = *(const bf16x8*)&sV[cur][nd * 16 + lr][((kk * 4 + lg) ^ swz) * 8];
        ctxa[nd] = MFMA16(paa, vf, ctxa[nd]);
        ctxb[nd] = MFMA16(pab, vf, ctxb[nd]);
      }
    }
    if (kt < 31) __syncthreads();          // drains this wave's DMA (vmcnt) + syncs buffer flip
  }

  // epilogue: ONE cross-lane reduce, normalize, store ctx + invl
  float lsa = (lacca[0] + lacca[1]) + (lacca[2] + lacca[3]);
  float lsb = (laccb[0] + laccb[1]) + (laccb[2] + laccb[3]);
  lsa += __shfl_xor(lsa, 16); lsa += __shfl_xor(lsa, 32);
  lsb += __shfl_xor(lsb, 16); lsb += __shfl_xor(lsb, 32);
  float ila = 1.0f / lsa, ilb = 1.0f / lsb;
  f32x4 ilva, ilvb;
#pragma unroll
  for (int r = 0; r < 4; r++) { ilva[r] = __shfl(ila, lg * 4 + r); ilvb[r] = __shfl(ilb, lg * 4 + r); }
#pragma unroll
  for (int nd = 0; nd < 4; nd++)
#pragma unroll
    for (int r = 0; r < 4; r++) {
      int ra = qa + lg * 4 + r, rb = qa + 16 + lg * 4 + r;
      ctx[(size_t)(b * SS + ra) * HH + h * HDIM + nd * 16 + lr] = (bf16)(ctxa[nd][r] * ilva[r]);
      ctx[(size_t)(b * SS + rb) * HH + h * HDIM + nd * 16 + lr] = (bf16)(ctxb[nd][r] * ilvb[r]);
    }
  if (l < 16) {
    invl[hb + qa + l]      = ila;
    invl[hb + qa + 16 + l] = ilb;
  }
}

// ---------------------------------------------------------------- head-summed mean: DMA-staged double-buffered K,
// one barrier per head; Q frags + invl prefetched one head ahead. Same source-swizzle scheme as attn_pv.
__global__ __launch_bounds__(256, 4) void attn_mean(const bf16* __restrict__ Q, const bf16* __restrict__ K,
                                                    const float* __restrict__ bias2,
                                                    const float* __restrict__ invl, float* __restrict__ meanOut) {
  int q0 = blockIdx.x * 128, kc0 = blockIdx.y * 64, b = blockIdx.z;
  int t = threadIdx.x, w = t >> 6, l = t & 63, lg = l >> 4, lr = l & 15;
  const float* biasb = bias2 + b * SS;
  __shared__ __align__(16) bf16 sK[2][64][64];   // 16 KB

  int rloc = l >> 3;
  int csw  = (l & 7) ^ (rloc & 7);
  int swz  = lr & 7;

  int qa = q0 + w * 32;
  int rowa = qa + lr, rowb = qa + 16 + lr;

  f32x4 bv[4];
#pragma unroll
  for (int ni = 0; ni < 4; ni++) bv[ni] = *(const f32x4*)&biasb[kc0 + ni * 16 + lg * 4];

  f32x4 zero4 = {0.f, 0.f, 0.f, 0.f};
  f32x4 macca[4], maccb[4];
#pragma unroll
  for (int ni = 0; ni < 4; ni++) { macca[ni] = zero4; maccb[ni] = zero4; }

  // prologue: DMA-stage h=0 K tile + load h=0 Q frags/invl
  bf16x8 qf0a, qf1a, qf0b, qf1b;
  float ila, ilb;
  {
    const bf16* Kh0 = K + ((size_t)b * NHEAD) * SS * HDIM;
#pragma unroll
    for (int i = 0; i < 2; i++) {
      int rs = w * 16 + i * 8;
      gload_lds16(Kh0 + (size_t)(kc0 + rs + rloc) * HDIM + csw * 8, &sK[0][rs][0]);
    }
    const bf16* Qh0 = Q + ((size_t)b * NHEAD) * SS * HDIM;
    qf0a = *(const bf16x8*)&Qh0[(size_t)rowa * HDIM + lg * 8];
    qf1a = *(const bf16x8*)&Qh0[(size_t)rowa * HDIM + 32 + lg * 8];
    qf0b = *(const bf16x8*)&Qh0[(size_t)rowb * HDIM + lg * 8];
    qf1b = *(const bf16x8*)&Qh0[(size_t)rowb * HDIM + 32 + lg * 8];
    size_t hb0 = (size_t)b * NHEAD * SS;
    ila = invl[hb0 + rowa] * (1.0f / NHEAD);
    ilb = invl[hb0 + rowb] * (1.0f / NHEAD);
  }
  __syncthreads();

  for (int h = 0; h < NHEAD; h++) {
    int cur = h & 1;
    bf16x8 qn0a, qn1a, qn0b, qn1b;
    float ina = 0.f, inb = 0.f;
    if (h < NHEAD - 1) {                   // DMA next head's K + prefetch Q/invl
      size_t hbn = ((size_t)b * NHEAD + h + 1) * SS;
      const bf16* Khn = K + hbn * HDIM;
#pragma unroll
      for (int i = 0; i < 2; i++) {
        int rs = w * 16 + i * 8;
        gload_lds16(Khn + (size_t)(kc0 + rs + rloc) * HDIM + csw * 8, &sK[cur ^ 1][rs][0]);
      }
      const bf16* Qhn = Q + hbn * HDIM;
      qn0a = *(const bf16x8*)&Qhn[(size_t)rowa * HDIM + lg * 8];
      qn1a = *(const bf16x8*)&Qhn[(size_t)rowa * HDIM + 32 + lg * 8];
      qn0b = *(const bf16x8*)&Qhn[(size_t)rowb * HDIM + lg * 8];
      qn1b = *(const bf16x8*)&Qhn[(size_t)rowb * HDIM + 32 + lg * 8];
      ina = invl[hbn + rowa] * (1.0f / NHEAD);
      inb = invl[hbn + rowb] * (1.0f / NHEAD);
    }
    // compute head h from sK[cur] (XOR-swizzled reads)
#pragma unroll
    for (int ni = 0; ni < 4; ni++) {
      bf16x8 kf0 = *(const bf16x8*)&sK[cur][ni * 16 + lr][(lg ^ swz) * 8];
      bf16x8 kf1 = *(const bf16x8*)&sK[cur][ni * 16 + lr][((4 + lg) ^ swz) * 8];
      f32x4 acca = MFMA16(kf1, qf1a, MFMA16(kf0, qf0a, zero4));
      f32x4 accb = MFMA16(kf1, qf1b, MFMA16(kf0, qf0b, zero4));
      f32x4 za = acca * SL + bv[ni];
      f32x4 zb = accb * SL + bv[ni];
#pragma unroll
      for (int r = 0; r < 4; r++) {
        macca[ni][r] += __builtin_amdgcn_exp2f(za[r]) * ila;
        maccb[ni][r] += __builtin_amdgcn_exp2f(zb[r]) * ilb;
      }
    }
    if (h < NHEAD - 1) {
      qf0a = qn0a; qf1a = qn1a; qf0b = qn0b; qf1b = qn1b;
      ila = ina; ilb = inb;
      __syncthreads();                     // drains DMA + buffer flip
    }
  }
  float* meanB = meanOut + (size_t)b * SS * SS;
#pragma unroll
  for (int ni = 0; ni < 4; ni++) {
    *(f32x4*)&meanB[(size_t)rowa * SS + kc0 + ni * 16 + lg * 4] = macca[ni];
    *(f32x4*)&meanB[(size_t)rowb * SS + kc0 + ni * 16 + lg * 4] = maccb[ni];
  }
}

// ---------------------------------------------------------------- launch
extern "C" void kernel_launch(void* const* d_in, const int* in_sizes, int n_in,
                              void* d_out, int out_size, void* d_ws, size_t ws_size,
                              hipStream_t stream) {
  const float* query  = (const float*)d_in[0];
  const float* key_in = (const float*)d_in[1];
  const float* value  = (const float*)d_in[2];
  const int*   mask   = (const int*)d_in[3];
  const float* Wq     = (const float*)d_in[4];
  const float* Wk     = (const float*)d_in[5];
  const float* Wv     = (const float*)d_in[6];
  const float* Wo     = (const float*)d_in[7];

  char* ws = (char*)d_ws;
  bf16*  Xb    = (bf16*)(ws);
  bf16*  Wt    = (bf16*)(ws + 25165824);
  bf16*  Qb    = (bf16*)(ws + 33554432);
  bf16*  Kb    = (bf16*)(ws + 41943040);
  bf16*  Vtb   = (bf16*)(ws + 50331648);
  float* invlb = (float*)(ws + 58982400);
  float* biasb = (float*)(ws + 59244544);
  bf16*  ctxb  = Xb;  // Xq dead after projections

  float* outF  = (float*)d_out;
  float* meanF = outF + (size_t)BB * SS * HH;  // second output: (B,S,S)

  cvt_in<<<4096, 256, 0, stream>>>(query, key_in, value, mask,
                                   Xb, Xb + 4194304, Xb + 8388608, biasb);
  cvt_wt<<<dim3(32, 32, 4), dim3(32, 8), 0, stream>>>(Wq, Wk, Wv, Wo, Wt);
  gemm128<<<dim3(8, 32, 3), 256, 0, stream>>>(Xb, Wt, Qb, Kb, Vtb, nullptr, -1);
  attn_pv<<<dim3(16, 16, 2), 256, 0, stream>>>(Qb, Kb, Vtb, biasb, invlb, ctxb);
  attn_mean<<<dim3(16, 32, 2), 256, 0, stream>>>(Qb, Kb, biasb, invlb, meanF);
  gemm128<<<dim3(8, 32, 1), 256, 0, stream>>>(ctxb, Wt + 3 * (size_t)HH * HH,
                                              nullptr, nullptr, nullptr, outF, 3);
}

// Round 13
// 192.513 us; speedup vs baseline: 1.0915x; 1.0915x over previous
//
#include <hip/hip_runtime.h>
#include <stdint.h>

#define BB 2
#define SS 2048
#define HH 1024
#define NHEAD 16
#define HDIM 64

constexpr int   BSROWS = BB * SS;   // 4096
constexpr float SCALE  = 0.125f;    // 1/sqrt(64)
constexpr float LOG2E  = 1.4426950408889634f;
constexpr float SL     = SCALE * LOG2E;

typedef __bf16 bf16;
typedef __attribute__((ext_vector_type(8))) __bf16 bf16x8;
typedef __attribute__((ext_vector_type(4))) __bf16 bf16x4;
typedef __attribute__((ext_vector_type(4))) float  f32x4;

#define MFMA16(a, b, c) __builtin_amdgcn_mfma_f32_16x16x32_bf16((a), (b), (c), 0, 0, 0)

__device__ __forceinline__ void gload_lds16(const void* g, void* l) {
  __builtin_amdgcn_global_load_lds((const __attribute__((address_space(1))) void*)g,
                                   (__attribute__((address_space(3))) void*)l, 16, 0, 0);
}

// ---------------------------------------------------------------- convert inputs (bias pre-scaled by LOG2E)
__global__ __launch_bounds__(256) void cvt_in(const float* __restrict__ q, const float* __restrict__ k,
                                              const float* __restrict__ v, const int* __restrict__ mask,
                                              bf16* __restrict__ xq, bf16* __restrict__ xk,
                                              bf16* __restrict__ xv, float* __restrict__ bias2) {
  int i = blockIdx.x * 256 + threadIdx.x;
  int e = i * 4;
  f32x4 a = *(const f32x4*)(q + e);
  f32x4 b = *(const f32x4*)(k + e);
  f32x4 c = *(const f32x4*)(v + e);
  *(bf16x4*)(xq + e) = __builtin_convertvector(a, bf16x4);
  *(bf16x4*)(xk + e) = __builtin_convertvector(b, bf16x4);
  *(bf16x4*)(xv + e) = __builtin_convertvector(c, bf16x4);
  if (i < BB * SS) bias2[i] = mask[i] ? 0.0f : -1e9f * LOG2E;
}

// ---------------------------------------------------------------- transpose + cast weights: Wt[n][k] = W[k][n]
__global__ __launch_bounds__(256) void cvt_wt(const float* __restrict__ Wq, const float* __restrict__ Wk,
                                              const float* __restrict__ Wv, const float* __restrict__ Wo,
                                              bf16* __restrict__ Wt) {
  __shared__ float tile[32][33];
  int z = blockIdx.z;
  const float* W = (z == 0) ? Wq : (z == 1) ? Wk : (z == 2) ? Wv : Wo;
  bf16* out = Wt + (size_t)z * HH * HH;
  int bx = blockIdx.x * 32, by = blockIdx.y * 32;
  int tx = threadIdx.x, ty = threadIdx.y;
#pragma unroll
  for (int j = 0; j < 32; j += 8)
    tile[ty + j][tx] = W[(size_t)(by + ty + j) * HH + bx + tx];
  __syncthreads();
#pragma unroll
  for (int j = 0; j < 32; j += 8)
    out[(size_t)(bx + ty + j) * HH + by + tx] = (bf16)tile[tx][ty + j];
}

// ---------------------------------------------------------------- 128x128 bf16 GEMM (m97 structure + XCD swizzle)
__global__ __launch_bounds__(256) void gemm128(const bf16* __restrict__ Abase, const bf16* __restrict__ Btbase,
                                               bf16* __restrict__ Qo, bf16* __restrict__ Ko,
                                               bf16* __restrict__ Vto, float* __restrict__ outF, int mode) {
  // XCD-aware swizzle: hw id -> logical tile so each XCD gets a contiguous chunk (nwg % 8 == 0)
  int id  = blockIdx.x + 8 * blockIdx.y + 256 * blockIdx.z;
  int nwg = 256 * gridDim.z;
  int sw  = (id & 7) * (nwg >> 3) + (id >> 3);
  int bx  = sw & 7, by = (sw >> 3) & 31, bz = sw >> 8;

  int zmode = (mode < 0) ? bz : mode;
  const bf16* A  = Abase  + (mode < 0 ? (size_t)bz * BSROWS * HH : 0);
  const bf16* Bt = Btbase + (mode < 0 ? (size_t)bz * HH * HH : 0);

  __shared__ __align__(16) bf16 lA[128 * 32];
  __shared__ __align__(16) bf16 lB[128 * 32];

  int t = threadIdx.x;
  int w = t >> 6, l = t & 63, lg = l >> 4, lr = l & 15;
  int m0 = by * 128, n0 = bx * 128;
  int wr = (w >> 1) * 64, wc = (w & 1) * 64;

  f32x4 zero4 = {0.f, 0.f, 0.f, 0.f};
  f32x4 acc[4][4];
#pragma unroll
  for (int i = 0; i < 4; i++)
#pragma unroll
    for (int j = 0; j < 4; j++) acc[i][j] = zero4;

  for (int k0 = 0; k0 < HH; k0 += 32) {
#pragma unroll
    for (int i = 0; i < 2; i++) {
      int idx = i * 256 + t;
      gload_lds16(A  + (size_t)(m0 + (idx >> 2)) * HH + k0 + (idx & 3) * 8, &lA[(i * 256 + w * 64) * 8]);
      gload_lds16(Bt + (size_t)(n0 + (idx >> 2)) * HH + k0 + (idx & 3) * 8, &lB[(i * 256 + w * 64) * 8]);
    }
    __syncthreads();
    bf16x8 af[4], bq[4];
#pragma unroll
    for (int mi = 0; mi < 4; mi++) af[mi] = *(const bf16x8*)&lA[(wr + mi * 16 + lr) * 32 + lg * 8];
#pragma unroll
    for (int ni = 0; ni < 4; ni++) bq[ni] = *(const bf16x8*)&lB[(wc + ni * 16 + lr) * 32 + lg * 8];
#pragma unroll
    for (int mi = 0; mi < 4; mi++)
#pragma unroll
      for (int ni = 0; ni < 4; ni++)
        acc[mi][ni] = MFMA16(af[mi], bq[ni], acc[mi][ni]);
    __syncthreads();
  }

#pragma unroll
  for (int mi = 0; mi < 4; mi++) {
    int row0 = m0 + wr + mi * 16 + lg * 4;
#pragma unroll
    for (int ni = 0; ni < 4; ni++) {
      int col = n0 + wc + ni * 16 + lr;
      if (zmode == 3) {
#pragma unroll
        for (int r = 0; r < 4; r++) outF[(size_t)(row0 + r) * HH + col] = acc[mi][ni][r];
      } else if (zmode == 2) {
        int b = row0 >> 11, s0 = row0 & (SS - 1);
        int h = col >> 6, d = col & 63;
        bf16x4 pk;
#pragma unroll
        for (int r = 0; r < 4; r++) pk[r] = (bf16)acc[mi][ni][r];
        *(bf16x4*)&Vto[((size_t)(b * NHEAD + h) * HDIM + d) * SS + s0] = pk;
      } else {
        bf16* dst = (zmode == 0) ? Qo : Ko;
        int h = col >> 6, d = col & 63;
#pragma unroll
        for (int r = 0; r < 4; r++) {
          int row = row0 + r;
          int b = row >> 11, s = row & (SS - 1);
          dst[((size_t)(b * NHEAD + h) * SS + s) * HDIM + d] = (bf16)acc[mi][ni][r];
        }
      }
    }
  }
}

// ---------------------------------------------------------------- flash without max-tracking (m = 0), reg-staged
// double-buffered K/V (proven R11 form) + XCD-chunked block swizzle (4 (b,h) groups per XCD -> K/V L2-resident).
__global__ __launch_bounds__(256, 2) void attn_pv(const bf16* __restrict__ Q, const bf16* __restrict__ K,
                                                  const bf16* __restrict__ Vt, const float* __restrict__ bias2,
                                                  float* __restrict__ invl, bf16* __restrict__ ctx) {
  int id = blockIdx.x + 16 * blockIdx.y + 256 * blockIdx.z;   // 512 blocks
  int sw = (id & 7) * 64 + (id >> 3);                          // bijective, 64 logical blocks per XCD
  int b = sw >> 8, h = (sw >> 4) & 15, q0 = (sw & 15) * 128;
  int t = threadIdx.x, w = t >> 6, l = t & 63, lg = l >> 4, lr = l & 15;
  size_t hb = ((size_t)b * NHEAD + h) * SS;
  const bf16* Qh = Q + hb * HDIM;
  const bf16* Kh = K + hb * HDIM;
  const bf16* Vh = Vt + ((size_t)b * NHEAD + h) * HDIM * SS;
  const float* biasb = bias2 + b * SS;

  __shared__ __align__(16) bf16 sK[64][72];   // K tile: rows=kcol, cols=dim
  __shared__ __align__(16) bf16 sV[64][72];   // V tile: rows=dim,  cols=kcol
  __shared__ __align__(16) bf16 lp[4][32][72];

  int r0 = t >> 3, c0 = (t & 7) * 8;          // staging: coalesced 16B chunks
  bf16x8 kreg[2], vreg[2];

  int qa = q0 + w * 32;                       // this wave's 32 q-rows
  int rowa = qa + lr, rowb = qa + 16 + lr;
  bf16x8 qf0a = *(const bf16x8*)&Qh[(size_t)rowa * HDIM + lg * 8];
  bf16x8 qf1a = *(const bf16x8*)&Qh[(size_t)rowa * HDIM + 32 + lg * 8];
  bf16x8 qf0b = *(const bf16x8*)&Qh[(size_t)rowb * HDIM + lg * 8];
  bf16x8 qf1b = *(const bf16x8*)&Qh[(size_t)rowb * HDIM + 32 + lg * 8];

  f32x4 zero4 = {0.f, 0.f, 0.f, 0.f};
  f32x4 lacca = zero4, laccb = zero4;         // per-lane partial softmax denominators
  f32x4 ctxa[4], ctxb[4];
#pragma unroll
  for (int nd = 0; nd < 4; nd++) { ctxa[nd] = zero4; ctxb[nd] = zero4; }

  // prologue: stage tile 0
#pragma unroll
  for (int i = 0; i < 2; i++) {
    int row = i * 32 + r0;
    kreg[i] = *(const bf16x8*)&Kh[(size_t)row * HDIM + c0];
    vreg[i] = *(const bf16x8*)&Vh[(size_t)row * SS + c0];
  }
#pragma unroll
  for (int i = 0; i < 2; i++) {
    int row = i * 32 + r0;
    *(bf16x8*)&sK[row][c0] = kreg[i];
    *(bf16x8*)&sV[row][c0] = vreg[i];
  }

  for (int kt = 0; kt < 32; kt++) {
    int k0 = kt * 64;
    __syncthreads();                      // staged tile visible
    if (kt < 31) {                        // issue next tile's loads early
      int kn = k0 + 64;
#pragma unroll
      for (int i = 0; i < 2; i++) {
        int row = i * 32 + r0;
        kreg[i] = *(const bf16x8*)&Kh[(size_t)(kn + row) * HDIM + c0];
        vreg[i] = *(const bf16x8*)&Vh[(size_t)row * SS + kn + c0];
      }
    }
    // ---- swapped QK^T: acc[ni][r] = S[kcol = ni*16+lg*4+r][qrow = lr (a) / 16+lr (b)]
    f32x4 acca[4], accb[4];
#pragma unroll
    for (int ni = 0; ni < 4; ni++) {
      const bf16* kp = &sK[ni * 16 + lr][lg * 8];
      bf16x8 kf0 = *(const bf16x8*)kp;
      bf16x8 kf1 = *(const bf16x8*)(kp + 32);
      acca[ni] = MFMA16(kf1, qf1a, MFMA16(kf0, qf0a, zero4));
      accb[ni] = MFMA16(kf1, qf1b, MFMA16(kf0, qf0b, zero4));
    }
    // ---- p = exp2(s*SL + bias2), fully lane-local; accumulate denominator partials
    f32x4 pa4[4], pb4[4];
#pragma unroll
    for (int ni = 0; ni < 4; ni++) {
      f32x4 bv = *(const f32x4*)&biasb[k0 + ni * 16 + lg * 4];
      f32x4 za = acca[ni] * SL + bv;
      f32x4 zb = accb[ni] * SL + bv;
#pragma unroll
      for (int r = 0; r < 4; r++) {
        pa4[ni][r] = __builtin_amdgcn_exp2f(za[r]);
        pb4[ni][r] = __builtin_amdgcn_exp2f(zb[r]);
      }
    }
    lacca += (pa4[0] + pa4[1]) + (pa4[2] + pa4[3]);
    laccb += (pb4[0] + pb4[1]) + (pb4[2] + pb4[3]);
#pragma unroll
    for (int ni = 0; ni < 4; ni++) {
      *(bf16x4*)&lp[w][lr][ni * 16 + lg * 4]      = __builtin_convertvector(pa4[ni], bf16x4);
      *(bf16x4*)&lp[w][16 + lr][ni * 16 + lg * 4] = __builtin_convertvector(pb4[ni], bf16x4);
    }
    // ---- PV from LDS (V frags shared by a/b); no rescale needed (m fixed)
#pragma unroll
    for (int kk = 0; kk < 2; kk++) {
      bf16x8 paa = *(const bf16x8*)&lp[w][lr][kk * 32 + lg * 8];
      bf16x8 pab = *(const bf16x8*)&lp[w][16 + lr][kk * 32 + lg * 8];
#pragma unroll
      for (int nd = 0; nd < 4; nd++) {
        bf16x8 vf = *(const bf16x8*)&sV[nd * 16 + lr][kk * 32 + lg * 8];
        ctxa[nd] = MFMA16(paa, vf, ctxa[nd]);
        ctxb[nd] = MFMA16(pab, vf, ctxb[nd]);
      }
    }
    __syncthreads();                      // all waves done reading this tile
    if (kt < 31) {
#pragma unroll
      for (int i = 0; i < 2; i++) {
        int row = i * 32 + r0;
        *(bf16x8*)&sK[row][c0] = kreg[i];
        *(bf16x8*)&sV[row][c0] = vreg[i];
      }
    }
  }

  // epilogue: ONE cross-lane reduce for the denominators, normalize, store ctx + invl
  float lsa = (lacca[0] + lacca[1]) + (lacca[2] + lacca[3]);
  float lsb = (laccb[0] + laccb[1]) + (laccb[2] + laccb[3]);
  lsa += __shfl_xor(lsa, 16); lsa += __shfl_xor(lsa, 32);
  lsb += __shfl_xor(lsb, 16); lsb += __shfl_xor(lsb, 32);
  float ila = 1.0f / lsa, ilb = 1.0f / lsb;
  f32x4 ilva, ilvb;
#pragma unroll
  for (int r = 0; r < 4; r++) { ilva[r] = __shfl(ila, lg * 4 + r); ilvb[r] = __shfl(ilb, lg * 4 + r); }
#pragma unroll
  for (int nd = 0; nd < 4; nd++)
#pragma unroll
    for (int r = 0; r < 4; r++) {
      int ra = qa + lg * 4 + r, rb = qa + 16 + lg * 4 + r;
      ctx[(size_t)(b * SS + ra) * HH + h * HDIM + nd * 16 + lr] = (bf16)(ctxa[nd][r] * ilva[r]);
      ctx[(size_t)(b * SS + rb) * HH + h * HDIM + nd * 16 + lr] = (bf16)(ctxb[nd][r] * ilvb[r]);
    }
  if (l < 16) {
    invl[hb + qa + l]      = ila;
    invl[hb + qa + 16 + l] = ilb;
  }
}

// ---------------------------------------------------------------- head-summed mean: DMA-staged double-buffered K,
// one barrier per head; Q frags + invl prefetched one head ahead; XCD-chunked block swizzle.
__global__ __launch_bounds__(256, 4) void attn_mean(const bf16* __restrict__ Q, const bf16* __restrict__ K,
                                                    const float* __restrict__ bias2,
                                                    const float* __restrict__ invl, float* __restrict__ meanOut) {
  int id = blockIdx.x + 16 * blockIdx.y + 512 * blockIdx.z;   // 1024 blocks
  int sw = (id & 7) * 128 + (id >> 3);                         // bijective, 128 logical blocks per XCD
  int b = sw >> 9, kc0 = ((sw >> 4) & 31) * 64, q0 = (sw & 15) * 128;
  int t = threadIdx.x, w = t >> 6, l = t & 63, lg = l >> 4, lr = l & 15;
  const float* biasb = bias2 + b * SS;
  __shared__ __align__(16) bf16 sK[2][64][64];   // 16 KB

  int rloc = l >> 3;
  int csw  = (l & 7) ^ (rloc & 7);
  int swz  = lr & 7;

  int qa = q0 + w * 32;
  int rowa = qa + lr, rowb = qa + 16 + lr;

  f32x4 bv[4];
#pragma unroll
  for (int ni = 0; ni < 4; ni++) bv[ni] = *(const f32x4*)&biasb[kc0 + ni * 16 + lg * 4];

  f32x4 zero4 = {0.f, 0.f, 0.f, 0.f};
  f32x4 macca[4], maccb[4];
#pragma unroll
  for (int ni = 0; ni < 4; ni++) { macca[ni] = zero4; maccb[ni] = zero4; }

  // prologue: DMA-stage h=0 K tile + load h=0 Q frags/invl
  bf16x8 qf0a, qf1a, qf0b, qf1b;
  float ila, ilb;
  {
    const bf16* Kh0 = K + ((size_t)b * NHEAD) * SS * HDIM;
#pragma unroll
    for (int i = 0; i < 2; i++) {
      int rs = w * 16 + i * 8;
      gload_lds16(Kh0 + (size_t)(kc0 + rs + rloc) * HDIM + csw * 8, &sK[0][rs][0]);
    }
    const bf16* Qh0 = Q + ((size_t)b * NHEAD) * SS * HDIM;
    qf0a = *(const bf16x8*)&Qh0[(size_t)rowa * HDIM + lg * 8];
    qf1a = *(const bf16x8*)&Qh0[(size_t)rowa * HDIM + 32 + lg * 8];
    qf0b = *(const bf16x8*)&Qh0[(size_t)rowb * HDIM + lg * 8];
    qf1b = *(const bf16x8*)&Qh0[(size_t)rowb * HDIM + 32 + lg * 8];
    size_t hb0 = (size_t)b * NHEAD * SS;
    ila = invl[hb0 + rowa] * (1.0f / NHEAD);
    ilb = invl[hb0 + rowb] * (1.0f / NHEAD);
  }
  __syncthreads();

  for (int h = 0; h < NHEAD; h++) {
    int cur = h & 1;
    bf16x8 qn0a, qn1a, qn0b, qn1b;
    float ina = 0.f, inb = 0.f;
    if (h < NHEAD - 1) {                   // DMA next head's K + prefetch Q/invl
      size_t hbn = ((size_t)b * NHEAD + h + 1) * SS;
      const bf16* Khn = K + hbn * HDIM;
#pragma unroll
      for (int i = 0; i < 2; i++) {
        int rs = w * 16 + i * 8;
        gload_lds16(Khn + (size_t)(kc0 + rs + rloc) * HDIM + csw * 8, &sK[cur ^ 1][rs][0]);
      }
      const bf16* Qhn = Q + hbn * HDIM;
      qn0a = *(const bf16x8*)&Qhn[(size_t)rowa * HDIM + lg * 8];
      qn1a = *(const bf16x8*)&Qhn[(size_t)rowa * HDIM + 32 + lg * 8];
      qn0b = *(const bf16x8*)&Qhn[(size_t)rowb * HDIM + lg * 8];
      qn1b = *(const bf16x8*)&Qhn[(size_t)rowb * HDIM + 32 + lg * 8];
      ina = invl[hbn + rowa] * (1.0f / NHEAD);
      inb = invl[hbn + rowb] * (1.0f / NHEAD);
    }
    // compute head h from sK[cur] (XOR-swizzled reads)
#pragma unroll
    for (int ni = 0; ni < 4; ni++) {
      bf16x8 kf0 = *(const bf16x8*)&sK[cur][ni * 16 + lr][(lg ^ swz) * 8];
      bf16x8 kf1 = *(const bf16x8*)&sK[cur][ni * 16 + lr][((4 + lg) ^ swz) * 8];
      f32x4 acca = MFMA16(kf1, qf1a, MFMA16(kf0, qf0a, zero4));
      f32x4 accb = MFMA16(kf1, qf1b, MFMA16(kf0, qf0b, zero4));
      f32x4 za = acca * SL + bv[ni];
      f32x4 zb = accb * SL + bv[ni];
#pragma unroll
      for (int r = 0; r < 4; r++) {
        macca[ni][r] += __builtin_amdgcn_exp2f(za[r]) * ila;
        maccb[ni][r] += __builtin_amdgcn_exp2f(zb[r]) * ilb;
      }
    }
    if (h < NHEAD - 1) {
      qf0a = qn0a; qf1a = qn1a; qf0b = qn0b; qf1b = qn1b;
      ila = ina; ilb = inb;
      __syncthreads();                     // drains DMA + buffer flip
    }
  }
  float* meanB = meanOut + (size_t)b * SS * SS;
#pragma unroll
  for (int ni = 0; ni < 4; ni++) {
    *(f32x4*)&meanB[(size_t)rowa * SS + kc0 + ni * 16 + lg * 4] = macca[ni];
    *(f32x4*)&meanB[(size_t)rowb * SS + kc0 + ni * 16 + lg * 4] = maccb[ni];
  }
}

// ---------------------------------------------------------------- launch
extern "C" void kernel_launch(void* const* d_in, const int* in_sizes, int n_in,
                              void* d_out, int out_size, void* d_ws, size_t ws_size,
                              hipStream_t stream) {
  const float* query  = (const float*)d_in[0];
  const float* key_in = (const float*)d_in[1];
  const float* value  = (const float*)d_in[2];
  const int*   mask   = (const int*)d_in[3];
  const float* Wq     = (const float*)d_in[4];
  const float* Wk     = (const float*)d_in[5];
  const float* Wv     = (const float*)d_in[6];
  const float* Wo     = (const float*)d_in[7];

  char* ws = (char*)d_ws;
  bf16*  Xb    = (bf16*)(ws);
  bf16*  Wt    = (bf16*)(ws + 25165824);
  bf16*  Qb    = (bf16*)(ws + 33554432);
  bf16*  Kb    = (bf16*)(ws + 41943040);
  bf16*  Vtb   = (bf16*)(ws + 50331648);
  float* invlb = (float*)(ws + 58982400);
  float* biasb = (float*)(ws + 59244544);
  bf16*  ctxb  = Xb;  // Xq dead after projections

  float* outF  = (float*)d_out;
  float* meanF = outF + (size_t)BB * SS * HH;  // second output: (B,S,S)

  cvt_in<<<4096, 256, 0, stream>>>(query, key_in, value, mask,
                                   Xb, Xb + 4194304, Xb + 8388608, biasb);
  cvt_wt<<<dim3(32, 32, 4), dim3(32, 8), 0, stream>>>(Wq, Wk, Wv, Wo, Wt);
  gemm128<<<dim3(8, 32, 3), 256, 0, stream>>>(Xb, Wt, Qb, Kb, Vtb, nullptr, -1);
  attn_pv<<<dim3(16, 16, 2), 256, 0, stream>>>(Qb, Kb, Vtb, biasb, invlb, ctxb);
  attn_mean<<<dim3(16, 32, 2), 256, 0, stream>>>(Qb, Kb, biasb, invlb, meanF);
  gemm128<<<dim3(8, 32, 1), 256, 0, stream>>>(ctxb, Wt + 3 * (size_t)HH * HH,
                                              nullptr, nullptr, nullptr, outF, 3);
}

// Round 14
// 180.262 us; speedup vs baseline: 1.1657x; 1.0680x over previous
//
#include <hip/hip_runtime.h>
#include <stdint.h>

#define BB 2
#define SS 2048
#define HH 1024
#define NHEAD 16
#define HDIM 64

constexpr int   BSROWS = BB * SS;   // 4096
constexpr float SCALE  = 0.125f;    // 1/sqrt(64)
constexpr float LOG2E  = 1.4426950408889634f;
constexpr float SL     = SCALE * LOG2E;

typedef __bf16 bf16;
typedef __attribute__((ext_vector_type(8))) __bf16 bf16x8;
typedef __attribute__((ext_vector_type(4))) __bf16 bf16x4;
typedef __attribute__((ext_vector_type(4))) float  f32x4;

#define MFMA16(a, b, c) __builtin_amdgcn_mfma_f32_16x16x32_bf16((a), (b), (c), 0, 0, 0)

__device__ __forceinline__ void gload_lds16(const void* g, void* l) {
  __builtin_amdgcn_global_load_lds((const __attribute__((address_space(1))) void*)g,
                                   (__attribute__((address_space(3))) void*)l, 16, 0, 0);
}

// ---------------------------------------------------------------- convert inputs (bias pre-scaled by LOG2E)
__global__ __launch_bounds__(256) void cvt_in(const float* __restrict__ q, const float* __restrict__ k,
                                              const float* __restrict__ v, const int* __restrict__ mask,
                                              bf16* __restrict__ xq, bf16* __restrict__ xk,
                                              bf16* __restrict__ xv, float* __restrict__ bias2) {
  int i = blockIdx.x * 256 + threadIdx.x;
  int e = i * 4;
  f32x4 a = *(const f32x4*)(q + e);
  f32x4 b = *(const f32x4*)(k + e);
  f32x4 c = *(const f32x4*)(v + e);
  *(bf16x4*)(xq + e) = __builtin_convertvector(a, bf16x4);
  *(bf16x4*)(xk + e) = __builtin_convertvector(b, bf16x4);
  *(bf16x4*)(xv + e) = __builtin_convertvector(c, bf16x4);
  if (i < BB * SS) bias2[i] = mask[i] ? 0.0f : -1e9f * LOG2E;
}

// ---------------------------------------------------------------- transpose + cast weights: Wt[n][k] = W[k][n]
__global__ __launch_bounds__(256) void cvt_wt(const float* __restrict__ Wq, const float* __restrict__ Wk,
                                              const float* __restrict__ Wv, const float* __restrict__ Wo,
                                              bf16* __restrict__ Wt) {
  __shared__ float tile[32][33];
  int z = blockIdx.z;
  const float* W = (z == 0) ? Wq : (z == 1) ? Wk : (z == 2) ? Wv : Wo;
  bf16* out = Wt + (size_t)z * HH * HH;
  int bx = blockIdx.x * 32, by = blockIdx.y * 32;
  int tx = threadIdx.x, ty = threadIdx.y;
#pragma unroll
  for (int j = 0; j < 32; j += 8)
    tile[ty + j][tx] = W[(size_t)(by + ty + j) * HH + bx + tx];
  __syncthreads();
#pragma unroll
  for (int j = 0; j < 32; j += 8)
    out[(size_t)(bx + ty + j) * HH + by + tx] = (bf16)tile[tx][ty + j];
}

// ---------------------------------------------------------------- 128x128 bf16 GEMM, 2-phase double-buffered
// (stage next tile's DMA, compute current, ONE barrier) + XCD-chunked swizzle.
__global__ __launch_bounds__(256) void gemm128(const bf16* __restrict__ Abase, const bf16* __restrict__ Btbase,
                                               bf16* __restrict__ Qo, bf16* __restrict__ Ko,
                                               bf16* __restrict__ Vto, float* __restrict__ outF, int mode) {
  int id  = blockIdx.x + 8 * blockIdx.y + 256 * blockIdx.z;
  int nwg = 256 * gridDim.z;
  int sw  = (id & 7) * (nwg >> 3) + (id >> 3);
  int bx  = sw & 7, by = (sw >> 3) & 31, bz = sw >> 8;

  int zmode = (mode < 0) ? bz : mode;
  const bf16* A  = Abase  + (mode < 0 ? (size_t)bz * BSROWS * HH : 0);
  const bf16* Bt = Btbase + (mode < 0 ? (size_t)bz * HH * HH : 0);

  __shared__ __align__(16) bf16 lA[2][128 * 32];
  __shared__ __align__(16) bf16 lB[2][128 * 32];

  int t = threadIdx.x;
  int w = t >> 6, l = t & 63, lg = l >> 4, lr = l & 15;
  int m0 = by * 128, n0 = bx * 128;
  int wr = (w >> 1) * 64, wc = (w & 1) * 64;

  f32x4 zero4 = {0.f, 0.f, 0.f, 0.f};
  f32x4 acc[4][4];
#pragma unroll
  for (int i = 0; i < 4; i++)
#pragma unroll
    for (int j = 0; j < 4; j++) acc[i][j] = zero4;

  // prologue: stage k-step 0 into buffer 0
#pragma unroll
  for (int i = 0; i < 2; i++) {
    int idx = i * 256 + t;
    gload_lds16(A  + (size_t)(m0 + (idx >> 2)) * HH + (idx & 3) * 8, &lA[0][(i * 256 + w * 64) * 8]);
    gload_lds16(Bt + (size_t)(n0 + (idx >> 2)) * HH + (idx & 3) * 8, &lB[0][(i * 256 + w * 64) * 8]);
  }
  __syncthreads();

  for (int kt = 0; kt < 32; kt++) {
    int cur = kt & 1;
    if (kt < 31) {                        // issue next k-step's DMA into the other buffer
      int kn = (kt + 1) * 32;
#pragma unroll
      for (int i = 0; i < 2; i++) {
        int idx = i * 256 + t;
        gload_lds16(A  + (size_t)(m0 + (idx >> 2)) * HH + kn + (idx & 3) * 8, &lA[cur ^ 1][(i * 256 + w * 64) * 8]);
        gload_lds16(Bt + (size_t)(n0 + (idx >> 2)) * HH + kn + (idx & 3) * 8, &lB[cur ^ 1][(i * 256 + w * 64) * 8]);
      }
    }
    bf16x8 af[4], bq[4];
#pragma unroll
    for (int mi = 0; mi < 4; mi++) af[mi] = *(const bf16x8*)&lA[cur][(wr + mi * 16 + lr) * 32 + lg * 8];
#pragma unroll
    for (int ni = 0; ni < 4; ni++) bq[ni] = *(const bf16x8*)&lB[cur][(wc + ni * 16 + lr) * 32 + lg * 8];
#pragma unroll
    for (int mi = 0; mi < 4; mi++)
#pragma unroll
      for (int ni = 0; ni < 4; ni++)
        acc[mi][ni] = MFMA16(af[mi], bq[ni], acc[mi][ni]);
    __syncthreads();                      // drains DMA (next buf ready) + guards reuse of current buf
  }

#pragma unroll
  for (int mi = 0; mi < 4; mi++) {
    int row0 = m0 + wr + mi * 16 + lg * 4;
#pragma unroll
    for (int ni = 0; ni < 4; ni++) {
      int col = n0 + wc + ni * 16 + lr;
      if (zmode == 3) {
#pragma unroll
        for (int r = 0; r < 4; r++) outF[(size_t)(row0 + r) * HH + col] = acc[mi][ni][r];
      } else if (zmode == 2) {
        int b = row0 >> 11, s0 = row0 & (SS - 1);
        int h = col >> 6, d = col & 63;
        bf16x4 pk;
#pragma unroll
        for (int r = 0; r < 4; r++) pk[r] = (bf16)acc[mi][ni][r];
        *(bf16x4*)&Vto[((size_t)(b * NHEAD + h) * HDIM + d) * SS + s0] = pk;
      } else {
        bf16* dst = (zmode == 0) ? Qo : Ko;
        int h = col >> 6, d = col & 63;
#pragma unroll
        for (int r = 0; r < 4; r++) {
          int row = row0 + r;
          int b = row >> 11, s = row & (SS - 1);
          dst[((size_t)(b * NHEAD + h) * SS + s) * HDIM + d] = (bf16)acc[mi][ni][r];
        }
      }
    }
  }
}

// ---------------------------------------------------------------- flash (m=0), reg-staged DOUBLE-buffered K/V,
// ONE barrier per tile, XCD-chunked swizzle. Per tile: issue loads(t+1) -> compute(buf) -> ds_write(buf^1) -> bar.
__global__ __launch_bounds__(256, 2) void attn_pv(const bf16* __restrict__ Q, const bf16* __restrict__ K,
                                                  const bf16* __restrict__ Vt, const float* __restrict__ bias2,
                                                  float* __restrict__ invl, bf16* __restrict__ ctx) {
  int id = blockIdx.x + 16 * blockIdx.y + 256 * blockIdx.z;   // 512 blocks
  int sw = (id & 7) * 64 + (id >> 3);                          // bijective, 64 logical blocks per XCD
  int b = sw >> 8, h = (sw >> 4) & 15, q0 = (sw & 15) * 128;
  int t = threadIdx.x, w = t >> 6, l = t & 63, lg = l >> 4, lr = l & 15;
  size_t hb = ((size_t)b * NHEAD + h) * SS;
  const bf16* Qh = Q + hb * HDIM;
  const bf16* Kh = K + hb * HDIM;
  const bf16* Vh = Vt + ((size_t)b * NHEAD + h) * HDIM * SS;
  const float* biasb = bias2 + b * SS;

  __shared__ __align__(16) bf16 sK[2][64][72];
  __shared__ __align__(16) bf16 sV[2][64][72];
  __shared__ __align__(16) bf16 lp[4][32][72];

  int r0 = t >> 3, c0 = (t & 7) * 8;          // staging: coalesced 16B chunks
  bf16x8 kreg[2], vreg[2];

  int qa = q0 + w * 32;                       // this wave's 32 q-rows
  int rowa = qa + lr, rowb = qa + 16 + lr;
  bf16x8 qf0a = *(const bf16x8*)&Qh[(size_t)rowa * HDIM + lg * 8];
  bf16x8 qf1a = *(const bf16x8*)&Qh[(size_t)rowa * HDIM + 32 + lg * 8];
  bf16x8 qf0b = *(const bf16x8*)&Qh[(size_t)rowb * HDIM + lg * 8];
  bf16x8 qf1b = *(const bf16x8*)&Qh[(size_t)rowb * HDIM + 32 + lg * 8];

  f32x4 zero4 = {0.f, 0.f, 0.f, 0.f};
  f32x4 lacca = zero4, laccb = zero4;         // per-lane partial softmax denominators
  f32x4 ctxa[4], ctxb[4];
#pragma unroll
  for (int nd = 0; nd < 4; nd++) { ctxa[nd] = zero4; ctxb[nd] = zero4; }

  // prologue: stage tile 0 into buffer 0
#pragma unroll
  for (int i = 0; i < 2; i++) {
    int row = i * 32 + r0;
    kreg[i] = *(const bf16x8*)&Kh[(size_t)row * HDIM + c0];
    vreg[i] = *(const bf16x8*)&Vh[(size_t)row * SS + c0];
  }
#pragma unroll
  for (int i = 0; i < 2; i++) {
    int row = i * 32 + r0;
    *(bf16x8*)&sK[0][row][c0] = kreg[i];
    *(bf16x8*)&sV[0][row][c0] = vreg[i];
  }
  __syncthreads();

  for (int kt = 0; kt < 32; kt++) {
    int k0 = kt * 64, cur = kt & 1;
    if (kt < 31) {                        // issue next tile's global loads (latency hides under compute)
      int kn = k0 + 64;
#pragma unroll
      for (int i = 0; i < 2; i++) {
        int row = i * 32 + r0;
        kreg[i] = *(const bf16x8*)&Kh[(size_t)(kn + row) * HDIM + c0];
        vreg[i] = *(const bf16x8*)&Vh[(size_t)row * SS + kn + c0];
      }
    }
    // ---- swapped QK^T: acc[ni][r] = S[kcol = ni*16+lg*4+r][qrow = lr (a) / 16+lr (b)]
    f32x4 acca[4], accb[4];
#pragma unroll
    for (int ni = 0; ni < 4; ni++) {
      const bf16* kp = &sK[cur][ni * 16 + lr][lg * 8];
      bf16x8 kf0 = *(const bf16x8*)kp;
      bf16x8 kf1 = *(const bf16x8*)(kp + 32);
      acca[ni] = MFMA16(kf1, qf1a, MFMA16(kf0, qf0a, zero4));
      accb[ni] = MFMA16(kf1, qf1b, MFMA16(kf0, qf0b, zero4));
    }
    // ---- p = exp2(s*SL + bias2), lane-local; accumulate denominator partials
    f32x4 pa4[4], pb4[4];
#pragma unroll
    for (int ni = 0; ni < 4; ni++) {
      f32x4 bv = *(const f32x4*)&biasb[k0 + ni * 16 + lg * 4];
      f32x4 za = acca[ni] * SL + bv;
      f32x4 zb = accb[ni] * SL + bv;
#pragma unroll
      for (int r = 0; r < 4; r++) {
        pa4[ni][r] = __builtin_amdgcn_exp2f(za[r]);
        pb4[ni][r] = __builtin_amdgcn_exp2f(zb[r]);
      }
    }
    lacca += (pa4[0] + pa4[1]) + (pa4[2] + pa4[3]);
    laccb += (pb4[0] + pb4[1]) + (pb4[2] + pb4[3]);
#pragma unroll
    for (int ni = 0; ni < 4; ni++) {
      *(bf16x4*)&lp[w][lr][ni * 16 + lg * 4]      = __builtin_convertvector(pa4[ni], bf16x4);
      *(bf16x4*)&lp[w][16 + lr][ni * 16 + lg * 4] = __builtin_convertvector(pb4[ni], bf16x4);
    }
    // ---- PV from LDS (V frags shared by a/b)
#pragma unroll
    for (int kk = 0; kk < 2; kk++) {
      bf16x8 paa = *(const bf16x8*)&lp[w][lr][kk * 32 + lg * 8];
      bf16x8 pab = *(const bf16x8*)&lp[w][16 + lr][kk * 32 + lg * 8];
#pragma unroll
      for (int nd = 0; nd < 4; nd++) {
        bf16x8 vf = *(const bf16x8*)&sV[cur][nd * 16 + lr][kk * 32 + lg * 8];
        ctxa[nd] = MFMA16(paa, vf, ctxa[nd]);
        ctxb[nd] = MFMA16(pab, vf, ctxb[nd]);
      }
    }
    if (kt < 31) {                        // write next tile into the other buffer; one barrier per tile
#pragma unroll
      for (int i = 0; i < 2; i++) {
        int row = i * 32 + r0;
        *(bf16x8*)&sK[cur ^ 1][row][c0] = kreg[i];
        *(bf16x8*)&sV[cur ^ 1][row][c0] = vreg[i];
      }
      __syncthreads();
    }
  }

  // epilogue: ONE cross-lane reduce for the denominators, normalize, store ctx + invl
  float lsa = (lacca[0] + lacca[1]) + (lacca[2] + lacca[3]);
  float lsb = (laccb[0] + laccb[1]) + (laccb[2] + laccb[3]);
  lsa += __shfl_xor(lsa, 16); lsa += __shfl_xor(lsa, 32);
  lsb += __shfl_xor(lsb, 16); lsb += __shfl_xor(lsb, 32);
  float ila = 1.0f / lsa, ilb = 1.0f / lsb;
  f32x4 ilva, ilvb;
#pragma unroll
  for (int r = 0; r < 4; r++) { ilva[r] = __shfl(ila, lg * 4 + r); ilvb[r] = __shfl(ilb, lg * 4 + r); }
#pragma unroll
  for (int nd = 0; nd < 4; nd++)
#pragma unroll
    for (int r = 0; r < 4; r++) {
      int ra = qa + lg * 4 + r, rb = qa + 16 + lg * 4 + r;
      ctx[(size_t)(b * SS + ra) * HH + h * HDIM + nd * 16 + lr] = (bf16)(ctxa[nd][r] * ilva[r]);
      ctx[(size_t)(b * SS + rb) * HH + h * HDIM + nd * 16 + lr] = (bf16)(ctxb[nd][r] * ilvb[r]);
    }
  if (l < 16) {
    invl[hb + qa + l]      = ila;
    invl[hb + qa + 16 + l] = ilb;
  }
}

// ---------------------------------------------------------------- head-summed mean: DMA-staged double-buffered K,
// one barrier per head; Q frags + invl prefetched one head ahead; XCD-chunked block swizzle.
__global__ __launch_bounds__(256, 4) void attn_mean(const bf16* __restrict__ Q, const bf16* __restrict__ K,
                                                    const float* __restrict__ bias2,
                                                    const float* __restrict__ invl, float* __restrict__ meanOut) {
  int id = blockIdx.x + 16 * blockIdx.y + 512 * blockIdx.z;   // 1024 blocks
  int sw = (id & 7) * 128 + (id >> 3);                         // bijective, 128 logical blocks per XCD
  int b = sw >> 9, kc0 = ((sw >> 4) & 31) * 64, q0 = (sw & 15) * 128;
  int t = threadIdx.x, w = t >> 6, l = t & 63, lg = l >> 4, lr = l & 15;
  const float* biasb = bias2 + b * SS;
  __shared__ __align__(16) bf16 sK[2][64][64];   // 16 KB

  int rloc = l >> 3;
  int csw  = (l & 7) ^ (rloc & 7);
  int swz  = lr & 7;

  int qa = q0 + w * 32;
  int rowa = qa + lr, rowb = qa + 16 + lr;

  f32x4 bv[4];
#pragma unroll
  for (int ni = 0; ni < 4; ni++) bv[ni] = *(const f32x4*)&biasb[kc0 + ni * 16 + lg * 4];

  f32x4 zero4 = {0.f, 0.f, 0.f, 0.f};
  f32x4 macca[4], maccb[4];
#pragma unroll
  for (int ni = 0; ni < 4; ni++) { macca[ni] = zero4; maccb[ni] = zero4; }

  // prologue: DMA-stage h=0 K tile + load h=0 Q frags/invl
  bf16x8 qf0a, qf1a, qf0b, qf1b;
  float ila, ilb;
  {
    const bf16* Kh0 = K + ((size_t)b * NHEAD) * SS * HDIM;
#pragma unroll
    for (int i = 0; i < 2; i++) {
      int rs = w * 16 + i * 8;
      gload_lds16(Kh0 + (size_t)(kc0 + rs + rloc) * HDIM + csw * 8, &sK[0][rs][0]);
    }
    const bf16* Qh0 = Q + ((size_t)b * NHEAD) * SS * HDIM;
    qf0a = *(const bf16x8*)&Qh0[(size_t)rowa * HDIM + lg * 8];
    qf1a = *(const bf16x8*)&Qh0[(size_t)rowa * HDIM + 32 + lg * 8];
    qf0b = *(const bf16x8*)&Qh0[(size_t)rowb * HDIM + lg * 8];
    qf1b = *(const bf16x8*)&Qh0[(size_t)rowb * HDIM + 32 + lg * 8];
    size_t hb0 = (size_t)b * NHEAD * SS;
    ila = invl[hb0 + rowa] * (1.0f / NHEAD);
    ilb = invl[hb0 + rowb] * (1.0f / NHEAD);
  }
  __syncthreads();

  for (int h = 0; h < NHEAD; h++) {
    int cur = h & 1;
    bf16x8 qn0a, qn1a, qn0b, qn1b;
    float ina = 0.f, inb = 0.f;
    if (h < NHEAD - 1) {                   // DMA next head's K + prefetch Q/invl
      size_t hbn = ((size_t)b * NHEAD + h + 1) * SS;
      const bf16* Khn = K + hbn * HDIM;
#pragma unroll
      for (int i = 0; i < 2; i++) {
        int rs = w * 16 + i * 8;
        gload_lds16(Khn + (size_t)(kc0 + rs + rloc) * HDIM + csw * 8, &sK[cur ^ 1][rs][0]);
      }
      const bf16* Qhn = Q + hbn * HDIM;
      qn0a = *(const bf16x8*)&Qhn[(size_t)rowa * HDIM + lg * 8];
      qn1a = *(const bf16x8*)&Qhn[(size_t)rowa * HDIM + 32 + lg * 8];
      qn0b = *(const bf16x8*)&Qhn[(size_t)rowb * HDIM + lg * 8];
      qn1b = *(const bf16x8*)&Qhn[(size_t)rowb * HDIM + 32 + lg * 8];
      ina = invl[hbn + rowa] * (1.0f / NHEAD);
      inb = invl[hbn + rowb] * (1.0f / NHEAD);
    }
    // compute head h from sK[cur] (XOR-swizzled reads)
#pragma unroll
    for (int ni = 0; ni < 4; ni++) {
      bf16x8 kf0 = *(const bf16x8*)&sK[cur][ni * 16 + lr][(lg ^ swz) * 8];
      bf16x8 kf1 = *(const bf16x8*)&sK[cur][ni * 16 + lr][((4 + lg) ^ swz) * 8];
      f32x4 acca = MFMA16(kf1, qf1a, MFMA16(kf0, qf0a, zero4));
      f32x4 accb = MFMA16(kf1, qf1b, MFMA16(kf0, qf0b, zero4));
      f32x4 za = acca * SL + bv[ni];
      f32x4 zb = accb * SL + bv[ni];
#pragma unroll
      for (int r = 0; r < 4; r++) {
        macca[ni][r] += __builtin_amdgcn_exp2f(za[r]) * ila;
        maccb[ni][r] += __builtin_amdgcn_exp2f(zb[r]) * ilb;
      }
    }
    if (h < NHEAD - 1) {
      qf0a = qn0a; qf1a = qn1a; qf0b = qn0b; qf1b = qn1b;
      ila = ina; ilb = inb;
      __syncthreads();                     // drains DMA + buffer flip
    }
  }
  float* meanB = meanOut + (size_t)b * SS * SS;
#pragma unroll
  for (int ni = 0; ni < 4; ni++) {
    *(f32x4*)&meanB[(size_t)rowa * SS + kc0 + ni * 16 + lg * 4] = macca[ni];
    *(f32x4*)&meanB[(size_t)rowb * SS + kc0 + ni * 16 + lg * 4] = maccb[ni];
  }
}

// ---------------------------------------------------------------- launch
extern "C" void kernel_launch(void* const* d_in, const int* in_sizes, int n_in,
                              void* d_out, int out_size, void* d_ws, size_t ws_size,
                              hipStream_t stream) {
  const float* query  = (const float*)d_in[0];
  const float* key_in = (const float*)d_in[1];
  const float* value  = (const float*)d_in[2];
  const int*   mask   = (const int*)d_in[3];
  const float* Wq     = (const float*)d_in[4];
  const float* Wk     = (const float*)d_in[5];
  const float* Wv     = (const float*)d_in[6];
  const float* Wo     = (const float*)d_in[7];

  char* ws = (char*)d_ws;
  bf16*  Xb    = (bf16*)(ws);
  bf16*  Wt    = (bf16*)(ws + 25165824);
  bf16*  Qb    = (bf16*)(ws + 33554432);
  bf16*  Kb    = (bf16*)(ws + 41943040);
  bf16*  Vtb   = (bf16*)(ws + 50331648);
  float* invlb = (float*)(ws + 58982400);
  float* biasb = (float*)(ws + 59244544);
  bf16*  ctxb  = Xb;  // Xq dead after projections

  float* outF  = (float*)d_out;
  float* meanF = outF + (size_t)BB * SS * HH;  // second output: (B,S,S)

  cvt_in<<<4096, 256, 0, stream>>>(query, key_in, value, mask,
                                   Xb, Xb + 4194304, Xb + 8388608, biasb);
  cvt_wt<<<dim3(32, 32, 4), dim3(32, 8), 0, stream>>>(Wq, Wk, Wv, Wo, Wt);
  gemm128<<<dim3(8, 32, 3), 256, 0, stream>>>(Xb, Wt, Qb, Kb, Vtb, nullptr, -1);
  attn_pv<<<dim3(16, 16, 2), 256, 0, stream>>>(Qb, Kb, Vtb, biasb, invlb, ctxb);
  attn_mean<<<dim3(16, 32, 2), 256, 0, stream>>>(Qb, Kb, biasb, invlb, meanF);
  gemm128<<<dim3(8, 32, 1), 256, 0, stream>>>(ctxb, Wt + 3 * (size_t)HH * HH,
                                              nullptr, nullptr, nullptr, outF, 3);
}

// Round 15
// 178.628 us; speedup vs baseline: 1.1763x; 1.0091x over previous
//
#include <hip/hip_runtime.h>
#include <stdint.h>

#define BB 2
#define SS 2048
#define HH 1024
#define NHEAD 16
#define HDIM 64

constexpr int   BSROWS = BB * SS;   // 4096
constexpr float SCALE  = 0.125f;    // 1/sqrt(64)
constexpr float LOG2E  = 1.4426950408889634f;
constexpr float SL     = SCALE * LOG2E;

typedef __bf16 bf16;
typedef __attribute__((ext_vector_type(8))) __bf16 bf16x8;
typedef __attribute__((ext_vector_type(4))) __bf16 bf16x4;
typedef __attribute__((ext_vector_type(4))) float  f32x4;

#define MFMA16(a, b, c) __builtin_amdgcn_mfma_f32_16x16x32_bf16((a), (b), (c), 0, 0, 0)

__device__ __forceinline__ void gload_lds16(const void* g, void* l) {
  __builtin_amdgcn_global_load_lds((const __attribute__((address_space(1))) void*)g,
                                   (__attribute__((address_space(3))) void*)l, 16, 0, 0);
}

// ---------------------------------------------------------------- convert inputs (bias pre-scaled by LOG2E)
__global__ __launch_bounds__(256) void cvt_in(const float* __restrict__ q, const float* __restrict__ k,
                                              const float* __restrict__ v, const int* __restrict__ mask,
                                              bf16* __restrict__ xq, bf16* __restrict__ xk,
                                              bf16* __restrict__ xv, float* __restrict__ bias2) {
  int i = blockIdx.x * 256 + threadIdx.x;
  int e = i * 4;
  f32x4 a = *(const f32x4*)(q + e);
  f32x4 b = *(const f32x4*)(k + e);
  f32x4 c = *(const f32x4*)(v + e);
  *(bf16x4*)(xq + e) = __builtin_convertvector(a, bf16x4);
  *(bf16x4*)(xk + e) = __builtin_convertvector(b, bf16x4);
  *(bf16x4*)(xv + e) = __builtin_convertvector(c, bf16x4);
  if (i < BB * SS) bias2[i] = mask[i] ? 0.0f : -1e9f * LOG2E;
}

// ---------------------------------------------------------------- transpose + cast weights: Wt[n][k] = W[k][n]
__global__ __launch_bounds__(256) void cvt_wt(const float* __restrict__ Wq, const float* __restrict__ Wk,
                                              const float* __restrict__ Wv, const float* __restrict__ Wo,
                                              bf16* __restrict__ Wt) {
  __shared__ float tile[32][33];
  int z = blockIdx.z;
  const float* W = (z == 0) ? Wq : (z == 1) ? Wk : (z == 2) ? Wv : Wo;
  bf16* out = Wt + (size_t)z * HH * HH;
  int bx = blockIdx.x * 32, by = blockIdx.y * 32;
  int tx = threadIdx.x, ty = threadIdx.y;
#pragma unroll
  for (int j = 0; j < 32; j += 8)
    tile[ty + j][tx] = W[(size_t)(by + ty + j) * HH + bx + tx];
  __syncthreads();
#pragma unroll
  for (int j = 0; j < 32; j += 8)
    out[(size_t)(bx + ty + j) * HH + by + tx] = (bf16)tile[tx][ty + j];
}

// ---------------------------------------------------------------- 128x128 bf16 GEMM, 2-phase double-buffered
// (stage next tile's DMA, compute current, ONE barrier) + XCD-chunked swizzle.
__global__ __launch_bounds__(256) void gemm128(const bf16* __restrict__ Abase, const bf16* __restrict__ Btbase,
                                               bf16* __restrict__ Qo, bf16* __restrict__ Ko,
                                               bf16* __restrict__ Vto, float* __restrict__ outF, int mode) {
  int id  = blockIdx.x + 8 * blockIdx.y + 256 * blockIdx.z;
  int nwg = 256 * gridDim.z;
  int sw  = (id & 7) * (nwg >> 3) + (id >> 3);
  int bx  = sw & 7, by = (sw >> 3) & 31, bz = sw >> 8;

  int zmode = (mode < 0) ? bz : mode;
  const bf16* A  = Abase  + (mode < 0 ? (size_t)bz * BSROWS * HH : 0);
  const bf16* Bt = Btbase + (mode < 0 ? (size_t)bz * HH * HH : 0);

  __shared__ __align__(16) bf16 lA[2][128 * 32];
  __shared__ __align__(16) bf16 lB[2][128 * 32];

  int t = threadIdx.x;
  int w = t >> 6, l = t & 63, lg = l >> 4, lr = l & 15;
  int m0 = by * 128, n0 = bx * 128;
  int wr = (w >> 1) * 64, wc = (w & 1) * 64;

  f32x4 zero4 = {0.f, 0.f, 0.f, 0.f};
  f32x4 acc[4][4];
#pragma unroll
  for (int i = 0; i < 4; i++)
#pragma unroll
    for (int j = 0; j < 4; j++) acc[i][j] = zero4;

  // prologue: stage k-step 0 into buffer 0
#pragma unroll
  for (int i = 0; i < 2; i++) {
    int idx = i * 256 + t;
    gload_lds16(A  + (size_t)(m0 + (idx >> 2)) * HH + (idx & 3) * 8, &lA[0][(i * 256 + w * 64) * 8]);
    gload_lds16(Bt + (size_t)(n0 + (idx >> 2)) * HH + (idx & 3) * 8, &lB[0][(i * 256 + w * 64) * 8]);
  }
  __syncthreads();

  for (int kt = 0; kt < 32; kt++) {
    int cur = kt & 1;
    if (kt < 31) {                        // issue next k-step's DMA into the other buffer
      int kn = (kt + 1) * 32;
#pragma unroll
      for (int i = 0; i < 2; i++) {
        int idx = i * 256 + t;
        gload_lds16(A  + (size_t)(m0 + (idx >> 2)) * HH + kn + (idx & 3) * 8, &lA[cur ^ 1][(i * 256 + w * 64) * 8]);
        gload_lds16(Bt + (size_t)(n0 + (idx >> 2)) * HH + kn + (idx & 3) * 8, &lB[cur ^ 1][(i * 256 + w * 64) * 8]);
      }
    }
    bf16x8 af[4], bq[4];
#pragma unroll
    for (int mi = 0; mi < 4; mi++) af[mi] = *(const bf16x8*)&lA[cur][(wr + mi * 16 + lr) * 32 + lg * 8];
#pragma unroll
    for (int ni = 0; ni < 4; ni++) bq[ni] = *(const bf16x8*)&lB[cur][(wc + ni * 16 + lr) * 32 + lg * 8];
#pragma unroll
    for (int mi = 0; mi < 4; mi++)
#pragma unroll
      for (int ni = 0; ni < 4; ni++)
        acc[mi][ni] = MFMA16(af[mi], bq[ni], acc[mi][ni]);
    __syncthreads();                      // drains DMA (next buf ready) + guards reuse of current buf
  }

#pragma unroll
  for (int mi = 0; mi < 4; mi++) {
    int row0 = m0 + wr + mi * 16 + lg * 4;
#pragma unroll
    for (int ni = 0; ni < 4; ni++) {
      int col = n0 + wc + ni * 16 + lr;
      if (zmode == 3) {
#pragma unroll
        for (int r = 0; r < 4; r++) outF[(size_t)(row0 + r) * HH + col] = acc[mi][ni][r];
      } else if (zmode == 2) {
        int b = row0 >> 11, s0 = row0 & (SS - 1);
        int h = col >> 6, d = col & 63;
        bf16x4 pk;
#pragma unroll
        for (int r = 0; r < 4; r++) pk[r] = (bf16)acc[mi][ni][r];
        *(bf16x4*)&Vto[((size_t)(b * NHEAD + h) * HDIM + d) * SS + s0] = pk;
      } else {
        bf16* dst = (zmode == 0) ? Qo : Ko;
        int h = col >> 6, d = col & 63;
#pragma unroll
        for (int r = 0; r < 4; r++) {
          int row = row0 + r;
          int b = row >> 11, s = row & (SS - 1);
          dst[((size_t)(b * NHEAD + h) * SS + s) * HDIM + d] = (bf16)acc[mi][ni][r];
        }
      }
    }
  }
}

// ---------------------------------------------------------------- flash (m=0), cross-tile software pipeline:
// PV(t-1) [from lp[prev] + V-frags held in regs] runs concurrently with QK(t)/softmax(t).
// Legal because m=0 => no ctx rescale. lp is wave-private (no barrier); ONE barrier per tile for sK/sV.
__global__ __launch_bounds__(256, 2) void attn_pv(const bf16* __restrict__ Q, const bf16* __restrict__ K,
                                                  const bf16* __restrict__ Vt, const float* __restrict__ bias2,
                                                  float* __restrict__ invl, bf16* __restrict__ ctx) {
  int id = blockIdx.x + 16 * blockIdx.y + 256 * blockIdx.z;   // 512 blocks
  int sw = (id & 7) * 64 + (id >> 3);                          // bijective, 64 logical blocks per XCD
  int b = sw >> 8, h = (sw >> 4) & 15, q0 = (sw & 15) * 128;
  int t = threadIdx.x, w = t >> 6, l = t & 63, lg = l >> 4, lr = l & 15;
  size_t hb = ((size_t)b * NHEAD + h) * SS;
  const bf16* Qh = Q + hb * HDIM;
  const bf16* Kh = K + hb * HDIM;
  const bf16* Vh = Vt + ((size_t)b * NHEAD + h) * HDIM * SS;
  const float* biasb = bias2 + b * SS;

  __shared__ __align__(16) bf16 sK[2][64][72];
  __shared__ __align__(16) bf16 sV[2][64][72];
  __shared__ __align__(16) bf16 lp[4][2][32][72];   // per-wave, double-buffered P

  int r0 = t >> 3, c0 = (t & 7) * 8;          // staging: coalesced 16B chunks
  bf16x8 kreg[2], vreg[2];

  int qa = q0 + w * 32;                       // this wave's 32 q-rows
  int rowa = qa + lr, rowb = qa + 16 + lr;
  bf16x8 qf0a = *(const bf16x8*)&Qh[(size_t)rowa * HDIM + lg * 8];
  bf16x8 qf1a = *(const bf16x8*)&Qh[(size_t)rowa * HDIM + 32 + lg * 8];
  bf16x8 qf0b = *(const bf16x8*)&Qh[(size_t)rowb * HDIM + lg * 8];
  bf16x8 qf1b = *(const bf16x8*)&Qh[(size_t)rowb * HDIM + 32 + lg * 8];

  f32x4 zero4 = {0.f, 0.f, 0.f, 0.f};
  f32x4 lacca = zero4, laccb = zero4;         // per-lane partial softmax denominators
  f32x4 ctxa[4], ctxb[4];
#pragma unroll
  for (int nd = 0; nd < 4; nd++) { ctxa[nd] = zero4; ctxb[nd] = zero4; }
  bf16x8 vh[2][4];                            // V(t) fragments held across one iteration (static-indexed)

  // prologue: stage tile 0 into buffer 0
#pragma unroll
  for (int i = 0; i < 2; i++) {
    int row = i * 32 + r0;
    kreg[i] = *(const bf16x8*)&Kh[(size_t)row * HDIM + c0];
    vreg[i] = *(const bf16x8*)&Vh[(size_t)row * SS + c0];
  }
#pragma unroll
  for (int i = 0; i < 2; i++) {
    int row = i * 32 + r0;
    *(bf16x8*)&sK[0][row][c0] = kreg[i];
    *(bf16x8*)&sV[0][row][c0] = vreg[i];
  }
  __syncthreads();

  for (int kt = 0; kt < 32; kt++) {
    int k0 = kt * 64, cur = kt & 1, prev = cur ^ 1;
    if (kt < 31) {                        // issue next tile's global loads (latency hides under compute)
      int kn = k0 + 64;
#pragma unroll
      for (int i = 0; i < 2; i++) {
        int row = i * 32 + r0;
        kreg[i] = *(const bf16x8*)&Kh[(size_t)(kn + row) * HDIM + c0];
        vreg[i] = *(const bf16x8*)&Vh[(size_t)row * SS + kn + c0];
      }
    }
    // ---- PV(t-1): lp[prev] (wave-private) x vh regs — independent of this tile's softmax
    if (kt > 0) {
#pragma unroll
      for (int kk = 0; kk < 2; kk++) {
        bf16x8 paa = *(const bf16x8*)&lp[w][prev][lr][kk * 32 + lg * 8];
        bf16x8 pab = *(const bf16x8*)&lp[w][prev][16 + lr][kk * 32 + lg * 8];
#pragma unroll
        for (int nd = 0; nd < 4; nd++) {
          ctxa[nd] = MFMA16(paa, vh[kk][nd], ctxa[nd]);
          ctxb[nd] = MFMA16(pab, vh[kk][nd], ctxb[nd]);
        }
      }
    }
    // ---- swapped QK^T(t): acc[ni][r] = S[kcol = ni*16+lg*4+r][qrow = lr (a) / 16+lr (b)]
    f32x4 acca[4], accb[4];
#pragma unroll
    for (int ni = 0; ni < 4; ni++) {
      const bf16* kp = &sK[cur][ni * 16 + lr][lg * 8];
      bf16x8 kf0 = *(const bf16x8*)kp;
      bf16x8 kf1 = *(const bf16x8*)(kp + 32);
      acca[ni] = MFMA16(kf1, qf1a, MFMA16(kf0, qf0a, zero4));
      accb[ni] = MFMA16(kf1, qf1b, MFMA16(kf0, qf0b, zero4));
    }
    // ---- read V(t) fragments into held registers (sV[cur] is stable this iteration)
#pragma unroll
    for (int kk = 0; kk < 2; kk++)
#pragma unroll
      for (int nd = 0; nd < 4; nd++)
        vh[kk][nd] = *(const bf16x8*)&sV[cur][nd * 16 + lr][kk * 32 + lg * 8];
    // ---- softmax(t): p = exp2(s*SL + bias2), lane-local; denominators; write lp[cur]
    f32x4 pa4[4], pb4[4];
#pragma unroll
    for (int ni = 0; ni < 4; ni++) {
      f32x4 bv = *(const f32x4*)&biasb[k0 + ni * 16 + lg * 4];
      f32x4 za = acca[ni] * SL + bv;
      f32x4 zb = accb[ni] * SL + bv;
#pragma unroll
      for (int r = 0; r < 4; r++) {
        pa4[ni][r] = __builtin_amdgcn_exp2f(za[r]);
        pb4[ni][r] = __builtin_amdgcn_exp2f(zb[r]);
      }
    }
    lacca += (pa4[0] + pa4[1]) + (pa4[2] + pa4[3]);
    laccb += (pb4[0] + pb4[1]) + (pb4[2] + pb4[3]);
#pragma unroll
    for (int ni = 0; ni < 4; ni++) {
      *(bf16x4*)&lp[w][cur][lr][ni * 16 + lg * 4]      = __builtin_convertvector(pa4[ni], bf16x4);
      *(bf16x4*)&lp[w][cur][16 + lr][ni * 16 + lg * 4] = __builtin_convertvector(pb4[ni], bf16x4);
    }
    // ---- stage next tile into the other buffer; one barrier per tile
    if (kt < 31) {
#pragma unroll
      for (int i = 0; i < 2; i++) {
        int row = i * 32 + r0;
        *(bf16x8*)&sK[prev][row][c0] = kreg[i];
        *(bf16x8*)&sV[prev][row][c0] = vreg[i];
      }
      __syncthreads();
    }
  }

  // drain: PV(31) — lp[cur of kt=31] = lp[1], vh = V(31)
#pragma unroll
  for (int kk = 0; kk < 2; kk++) {
    bf16x8 paa = *(const bf16x8*)&lp[w][1][lr][kk * 32 + lg * 8];
    bf16x8 pab = *(const bf16x8*)&lp[w][1][16 + lr][kk * 32 + lg * 8];
#pragma unroll
    for (int nd = 0; nd < 4; nd++) {
      ctxa[nd] = MFMA16(paa, vh[kk][nd], ctxa[nd]);
      ctxb[nd] = MFMA16(pab, vh[kk][nd], ctxb[nd]);
    }
  }

  // epilogue: ONE cross-lane reduce for the denominators, normalize, store ctx + invl
  float lsa = (lacca[0] + lacca[1]) + (lacca[2] + lacca[3]);
  float lsb = (laccb[0] + laccb[1]) + (laccb[2] + laccb[3]);
  lsa += __shfl_xor(lsa, 16); lsa += __shfl_xor(lsa, 32);
  lsb += __shfl_xor(lsb, 16); lsb += __shfl_xor(lsb, 32);
  float ila = 1.0f / lsa, ilb = 1.0f / lsb;
  f32x4 ilva, ilvb;
#pragma unroll
  for (int r = 0; r < 4; r++) { ilva[r] = __shfl(ila, lg * 4 + r); ilvb[r] = __shfl(ilb, lg * 4 + r); }
#pragma unroll
  for (int nd = 0; nd < 4; nd++)
#pragma unroll
    for (int r = 0; r < 4; r++) {
      int ra = qa + lg * 4 + r, rb = qa + 16 + lg * 4 + r;
      ctx[(size_t)(b * SS + ra) * HH + h * HDIM + nd * 16 + lr] = (bf16)(ctxa[nd][r] * ilva[r]);
      ctx[(size_t)(b * SS + rb) * HH + h * HDIM + nd * 16 + lr] = (bf16)(ctxb[nd][r] * ilvb[r]);
    }
  if (l < 16) {
    invl[hb + qa + l]      = ila;
    invl[hb + qa + 16 + l] = ilb;
  }
}

// ---------------------------------------------------------------- head-summed mean: DMA-staged double-buffered K,
// one barrier per head; Q frags + invl prefetched one head ahead; XCD-chunked block swizzle.
__global__ __launch_bounds__(256, 4) void attn_mean(const bf16* __restrict__ Q, const bf16* __restrict__ K,
                                                    const float* __restrict__ bias2,
                                                    const float* __restrict__ invl, float* __restrict__ meanOut) {
  int id = blockIdx.x + 16 * blockIdx.y + 512 * blockIdx.z;   // 1024 blocks
  int sw = (id & 7) * 128 + (id >> 3);                         // bijective, 128 logical blocks per XCD
  int b = sw >> 9, kc0 = ((sw >> 4) & 31) * 64, q0 = (sw & 15) * 128;
  int t = threadIdx.x, w = t >> 6, l = t & 63, lg = l >> 4, lr = l & 15;
  const float* biasb = bias2 + b * SS;
  __shared__ __align__(16) bf16 sK[2][64][64];   // 16 KB

  int rloc = l >> 3;
  int csw  = (l & 7) ^ (rloc & 7);
  int swz  = lr & 7;

  int qa = q0 + w * 32;
  int rowa = qa + lr, rowb = qa + 16 + lr;

  f32x4 bv[4];
#pragma unroll
  for (int ni = 0; ni < 4; ni++) bv[ni] = *(const f32x4*)&biasb[kc0 + ni * 16 + lg * 4];

  f32x4 zero4 = {0.f, 0.f, 0.f, 0.f};
  f32x4 macca[4], maccb[4];
#pragma unroll
  for (int ni = 0; ni < 4; ni++) { macca[ni] = zero4; maccb[ni] = zero4; }

  // prologue: DMA-stage h=0 K tile + load h=0 Q frags/invl
  bf16x8 qf0a, qf1a, qf0b, qf1b;
  float ila, ilb;
  {
    const bf16* Kh0 = K + ((size_t)b * NHEAD) * SS * HDIM;
#pragma unroll
    for (int i = 0; i < 2; i++) {
      int rs = w * 16 + i * 8;
      gload_lds16(Kh0 + (size_t)(kc0 + rs + rloc) * HDIM + csw * 8, &sK[0][rs][0]);
    }
    const bf16* Qh0 = Q + ((size_t)b * NHEAD) * SS * HDIM;
    qf0a = *(const bf16x8*)&Qh0[(size_t)rowa * HDIM + lg * 8];
    qf1a = *(const bf16x8*)&Qh0[(size_t)rowa * HDIM + 32 + lg * 8];
    qf0b = *(const bf16x8*)&Qh0[(size_t)rowb * HDIM + lg * 8];
    qf1b = *(const bf16x8*)&Qh0[(size_t)rowb * HDIM + 32 + lg * 8];
    size_t hb0 = (size_t)b * NHEAD * SS;
    ila = invl[hb0 + rowa] * (1.0f / NHEAD);
    ilb = invl[hb0 + rowb] * (1.0f / NHEAD);
  }
  __syncthreads();

  for (int h = 0; h < NHEAD; h++) {
    int cur = h & 1;
    bf16x8 qn0a, qn1a, qn0b, qn1b;
    float ina = 0.f, inb = 0.f;
    if (h < NHEAD - 1) {                   // DMA next head's K + prefetch Q/invl
      size_t hbn = ((size_t)b * NHEAD + h + 1) * SS;
      const bf16* Khn = K + hbn * HDIM;
#pragma unroll
      for (int i = 0; i < 2; i++) {
        int rs = w * 16 + i * 8;
        gload_lds16(Khn + (size_t)(kc0 + rs + rloc) * HDIM + csw * 8, &sK[cur ^ 1][rs][0]);
      }
      const bf16* Qhn = Q + hbn * HDIM;
      qn0a = *(const bf16x8*)&Qhn[(size_t)rowa * HDIM + lg * 8];
      qn1a = *(const bf16x8*)&Qhn[(size_t)rowa * HDIM + 32 + lg * 8];
      qn0b = *(const bf16x8*)&Qhn[(size_t)rowb * HDIM + lg * 8];
      qn1b = *(const bf16x8*)&Qhn[(size_t)rowb * HDIM + 32 + lg * 8];
      ina = invl[hbn + rowa] * (1.0f / NHEAD);
      inb = invl[hbn + rowb] * (1.0f / NHEAD);
    }
    // compute head h from sK[cur] (XOR-swizzled reads)
#pragma unroll
    for (int ni = 0; ni < 4; ni++) {
      bf16x8 kf0 = *(const bf16x8*)&sK[cur][ni * 16 + lr][(lg ^ swz) * 8];
      bf16x8 kf1 = *(const bf16x8*)&sK[cur][ni * 16 + lr][((4 + lg) ^ swz) * 8];
      f32x4 acca = MFMA16(kf1, qf1a, MFMA16(kf0, qf0a, zero4));
      f32x4 accb = MFMA16(kf1, qf1b, MFMA16(kf0, qf0b, zero4));
      f32x4 za = acca * SL + bv[ni];
      f32x4 zb = accb * SL + bv[ni];
#pragma unroll
      for (int r = 0; r < 4; r++) {
        macca[ni][r] += __builtin_amdgcn_exp2f(za[r]) * ila;
        maccb[ni][r] += __builtin_amdgcn_exp2f(zb[r]) * ilb;
      }
    }
    if (h < NHEAD - 1) {
      qf0a = qn0a; qf1a = qn1a; qf0b = qn0b; qf1b = qn1b;
      ila = ina; ilb = inb;
      __syncthreads();                     // drains DMA + buffer flip
    }
  }
  float* meanB = meanOut + (size_t)b * SS * SS;
#pragma unroll
  for (int ni = 0; ni < 4; ni++) {
    *(f32x4*)&meanB[(size_t)rowa * SS + kc0 + ni * 16 + lg * 4] = macca[ni];
    *(f32x4*)&meanB[(size_t)rowb * SS + kc0 + ni * 16 + lg * 4] = maccb[ni];
  }
}

// ---------------------------------------------------------------- launch
extern "C" void kernel_launch(void* const* d_in, const int* in_sizes, int n_in,
                              void* d_out, int out_size, void* d_ws, size_t ws_size,
                              hipStream_t stream) {
  const float* query  = (const float*)d_in[0];
  const float* key_in = (const float*)d_in[1];
  const float* value  = (const float*)d_in[2];
  const int*   mask   = (const int*)d_in[3];
  const float* Wq     = (const float*)d_in[4];
  const float* Wk     = (const float*)d_in[5];
  const float* Wv     = (const float*)d_in[6];
  const float* Wo     = (const float*)d_in[7];

  char* ws = (char*)d_ws;
  bf16*  Xb    = (bf16*)(ws);
  bf16*  Wt    = (bf16*)(ws + 25165824);
  bf16*  Qb    = (bf16*)(ws + 33554432);
  bf16*  Kb    = (bf16*)(ws + 41943040);
  bf16*  Vtb   = (bf16*)(ws + 50331648);
  float* invlb = (float*)(ws + 58982400);
  float* biasb = (float*)(ws + 59244544);
  bf16*  ctxb  = Xb;  // Xq dead after projections

  float* outF  = (float*)d_out;
  float* meanF = outF + (size_t)BB * SS * HH;  // second output: (B,S,S)

  cvt_in<<<4096, 256, 0, stream>>>(query, key_in, value, mask,
                                   Xb, Xb + 4194304, Xb + 8388608, biasb);
  cvt_wt<<<dim3(32, 32, 4), dim3(32, 8), 0, stream>>>(Wq, Wk, Wv, Wo, Wt);
  gemm128<<<dim3(8, 32, 3), 256, 0, stream>>>(Xb, Wt, Qb, Kb, Vtb, nullptr, -1);
  attn_pv<<<dim3(16, 16, 2), 256, 0, stream>>>(Qb, Kb, Vtb, biasb, invlb, ctxb);
  attn_mean<<<dim3(16, 32, 2), 256, 0, stream>>>(Qb, Kb, biasb, invlb, meanF);
  gemm128<<<dim3(8, 32, 1), 256, 0, stream>>>(ctxb, Wt + 3 * (size_t)HH * HH,
                                              nullptr, nullptr, nullptr, outF, 3);
}